// Round 1
// baseline (777.254 us; speedup 1.0000x reference)
//
#include <hip/hip_runtime.h>

// Spatial Transformer Network, fully fused: one block per image.
// Image [28][28][3] -> LDS (CHW), localization net entirely in LDS/regs,
// affine grid + bilinear sample reusing the LDS image, staged output copy.

__launch_bounds__(256, 2)
__global__ void stn_fused_kernel(
    const float* __restrict__ x,
    const float* __restrict__ w1, const float* __restrict__ b1,
    const float* __restrict__ w2, const float* __restrict__ b2,
    const float* __restrict__ fc1w, const float* __restrict__ fc1b,
    const float* __restrict__ fc2w, const float* __restrict__ fc2b,
    float* __restrict__ out)
{
    __shared__ __align__(16) float s_img[3 * 28 * 28];   // 2352, CHW
    __shared__ __align__(16) float s_w1[8 * 3 * 7 * 7];  // 1176
    __shared__ float s_b1[8];
    __shared__ __align__(16) float s_w2[10 * 8 * 5 * 5]; // 2000
    __shared__ float s_b2[10];
    __shared__ __align__(16) float s_fc1w[32 * 90];      // 2880
    __shared__ float s_fc1b[32];
    __shared__ __align__(16) float s_fc2w[6 * 32];       // 192
    __shared__ float s_fc2b[6];
    __shared__ __align__(16) float s_c1[8 * 22 * 22];    // 3872 conv1 out; reused as output staging
    __shared__ __align__(16) float s_h1[8 * 11 * 12];    // pooled1, rows padded to 12
    __shared__ __align__(16) float s_c2[10 * 7 * 8];     // conv2 out, rows padded to 8
    __shared__ float s_h2[90];
    __shared__ float s_fch[32];
    __shared__ float s_theta[6];

    const int t = threadIdx.x;
    const int n = blockIdx.x;
    const float* img = x + (size_t)n * 2352;

    // ---- Stage A: cooperative loads (image HWC -> LDS CHW, plus all weights)
    for (int i = t; i < 2352; i += 256) {
        int hw = i / 3;
        int c = i - 3 * hw;
        s_img[c * 784 + hw] = img[i];
    }
    for (int i = t; i < 1176; i += 256) s_w1[i] = w1[i];
    for (int i = t; i < 2000; i += 256) s_w2[i] = w2[i];
    for (int i = t; i < 2880; i += 256) s_fc1w[i] = fc1w[i];
    if (t < 192) s_fc2w[t] = fc2w[t];
    if (t < 8)  s_b1[t] = b1[t];
    if (t < 10) s_b2[t] = b2[t];
    if (t < 32) s_fc1b[t] = fc1b[t];
    if (t < 6)  s_fc2b[t] = fc2b[t];
    __syncthreads();

    // ---- Stage B: conv1 (3->8, 7x7 valid) -> s_c1 [8][22][22]
    // Thread (o, i) computes one full 22-wide output row in registers.
    if (t < 176) {
        const int o = t / 22, i = t - 22 * (t / 22);
        float acc[22];
        const float bias = s_b1[o];
        #pragma unroll
        for (int j = 0; j < 22; ++j) acc[j] = bias;
        for (int c = 0; c < 3; ++c) {
            for (int kh = 0; kh < 7; ++kh) {
                const float* irow = &s_img[c * 784 + (i + kh) * 28];
                float im[28];
                #pragma unroll
                for (int q = 0; q < 7; ++q) {
                    float4 v = ((const float4*)irow)[q];
                    im[4 * q + 0] = v.x; im[4 * q + 1] = v.y;
                    im[4 * q + 2] = v.z; im[4 * q + 3] = v.w;
                }
                const float* wr = &s_w1[((o * 3 + c) * 7 + kh) * 7];
                float wv[7];
                #pragma unroll
                for (int q = 0; q < 7; ++q) wv[q] = wr[q];
                #pragma unroll
                for (int kw = 0; kw < 7; ++kw) {
                    #pragma unroll
                    for (int j = 0; j < 22; ++j)
                        acc[j] += im[j + kw] * wv[kw];
                }
            }
        }
        float* orow = &s_c1[(o * 22 + i) * 22];
        #pragma unroll
        for (int j = 0; j < 22; ++j) orow[j] = acc[j];
    }
    __syncthreads();

    // ---- Stage C: maxpool 2x2 + relu -> s_h1 [8][11][12pad]
    for (int u = t; u < 968; u += 256) {
        int o = u / 121, r = u - 121 * o;
        int ph = r / 11, pw = r - 11 * ph;
        const float* base = &s_c1[(o * 22 + 2 * ph) * 22 + 2 * pw];
        float m = fmaxf(fmaxf(base[0], base[1]), fmaxf(base[22], base[23]));
        s_h1[(o * 11 + ph) * 12 + pw] = fmaxf(m, 0.0f);
    }
    __syncthreads();

    // ---- Stage D: conv2 (8->10, 5x5 valid) -> s_c2 [10][7][8pad]
    if (t < 70) {
        const int o = t / 7, i = t - 7 * (t / 7);
        float acc[7];
        const float bias = s_b2[o];
        #pragma unroll
        for (int j = 0; j < 7; ++j) acc[j] = bias;
        for (int c = 0; c < 8; ++c) {
            #pragma unroll
            for (int kh = 0; kh < 5; ++kh) {
                const float* hrow = &s_h1[(c * 11 + i + kh) * 12];
                float im[12];
                #pragma unroll
                for (int q = 0; q < 3; ++q) {
                    float4 v = ((const float4*)hrow)[q];
                    im[4 * q + 0] = v.x; im[4 * q + 1] = v.y;
                    im[4 * q + 2] = v.z; im[4 * q + 3] = v.w;
                }
                const float* wr = &s_w2[((o * 8 + c) * 5 + kh) * 5];
                float wv[5];
                #pragma unroll
                for (int q = 0; q < 5; ++q) wv[q] = wr[q];
                #pragma unroll
                for (int kw = 0; kw < 5; ++kw) {
                    #pragma unroll
                    for (int j = 0; j < 7; ++j)
                        acc[j] += im[j + kw] * wv[kw];
                }
            }
        }
        float* orow = &s_c2[(o * 7 + i) * 8];
        #pragma unroll
        for (int j = 0; j < 7; ++j) orow[j] = acc[j];
    }
    __syncthreads();

    // ---- Stage E: maxpool 2x2 + relu -> s_h2[90] (c*9 + ph*3 + pw order)
    if (t < 90) {
        int o = t / 9, r = t - 9 * o;
        int ph = r / 3, pw = r - 3 * ph;
        const float* base = &s_c2[(o * 7 + 2 * ph) * 8 + 2 * pw];
        float m = fmaxf(fmaxf(base[0], base[1]), fmaxf(base[8], base[9]));
        s_h2[t] = fmaxf(m, 0.0f);
    }
    __syncthreads();

    // ---- Stage F: fc1 (90->32) + relu
    if (t < 32) {
        float acc = s_fc1b[t];
        const float* wr = &s_fc1w[t * 90];
        #pragma unroll 6
        for (int j = 0; j < 90; ++j) acc += s_h2[j] * wr[j];
        s_fch[t] = fmaxf(acc, 0.0f);
    }
    __syncthreads();

    // ---- Stage G: fc2 (32->6) -> theta
    if (t < 6) {
        float acc = s_fc2b[t];
        const float* wr = &s_fc2w[t * 32];
        #pragma unroll
        for (int j = 0; j < 32; ++j) acc += s_fch[j] * wr[j];
        s_theta[t] = acc;
    }
    __syncthreads();

    const float t00 = s_theta[0], t01 = s_theta[1], t02 = s_theta[2];
    const float t10 = s_theta[3], t11 = s_theta[4], t12 = s_theta[5];

    // ---- Stage H: affine grid + bilinear sample (zeros padding) -> staging in s_c1
    for (int p = t; p < 784; p += 256) {
        int h = p / 28, w = p - 28 * h;
        float xs = (2.0f * w + 1.0f) * (1.0f / 28.0f) - 1.0f;
        float ys = (2.0f * h + 1.0f) * (1.0f / 28.0f) - 1.0f;
        float gx = t00 * xs + t01 * ys + t02;
        float gy = t10 * xs + t11 * ys + t12;
        float ix = ((gx + 1.0f) * 28.0f - 1.0f) * 0.5f;
        float iy = ((gy + 1.0f) * 28.0f - 1.0f) * 0.5f;
        float x0f = floorf(ix), y0f = floorf(iy);
        float wx1 = ix - x0f, wx0 = 1.0f - wx1;
        float wy1 = iy - y0f, wy0 = 1.0f - wy1;
        int x0 = (int)x0f, y0 = (int)y0f;
        int x1 = x0 + 1, y1 = y0 + 1;
        float fx0 = (x0 >= 0 && x0 < 28) ? 1.0f : 0.0f;
        float fx1 = (x1 >= 0 && x1 < 28) ? 1.0f : 0.0f;
        float fy0 = (y0 >= 0 && y0 < 28) ? 1.0f : 0.0f;
        float fy1 = (y1 >= 0 && y1 < 28) ? 1.0f : 0.0f;
        float w00 = wx0 * wy0 * fx0 * fy0;
        float w10 = wx1 * wy0 * fx1 * fy0;
        float w01 = wx0 * wy1 * fx0 * fy1;
        float w11 = wx1 * wy1 * fx1 * fy1;
        int cx0 = min(max(x0, 0), 27), cx1 = min(max(x1, 0), 27);
        int cy0 = min(max(y0, 0), 27), cy1 = min(max(y1, 0), 27);
        int i00 = cy0 * 28 + cx0, i10 = cy0 * 28 + cx1;
        int i01 = cy1 * 28 + cx0, i11 = cy1 * 28 + cx1;
        #pragma unroll
        for (int c = 0; c < 3; ++c) {
            const float* ic = &s_img[c * 784];
            float v = ic[i00] * w00 + ic[i10] * w10 + ic[i01] * w01 + ic[i11] * w11;
            s_c1[p * 3 + c] = v;  // HWC staging, matches output layout
        }
    }
    __syncthreads();

    // ---- Stage I: coalesced float4 copy staging -> global
    float* outp = out + (size_t)n * 2352;
    for (int i = t; i < 588; i += 256) {
        ((float4*)outp)[i] = ((const float4*)s_c1)[i];
    }
}

extern "C" void kernel_launch(void* const* d_in, const int* in_sizes, int n_in,
                              void* d_out, int out_size, void* d_ws, size_t ws_size,
                              hipStream_t stream) {
    const float* x     = (const float*)d_in[0];
    const float* w1    = (const float*)d_in[1];
    const float* b1    = (const float*)d_in[2];
    const float* w2    = (const float*)d_in[3];
    const float* b2    = (const float*)d_in[4];
    const float* fc1w  = (const float*)d_in[5];
    const float* fc1b  = (const float*)d_in[6];
    const float* fc2w  = (const float*)d_in[7];
    const float* fc2b  = (const float*)d_in[8];
    float* outp = (float*)d_out;

    const int n_img = 64 * 256;  // b*n
    stn_fused_kernel<<<dim3(n_img), dim3(256), 0, stream>>>(
        x, w1, b1, w2, b2, fc1w, fc1b, fc2w, fc2b, outp);
}

// Round 2
// 450.864 us; speedup vs baseline: 1.7239x; 1.7239x over previous
//
#include <hip/hip_runtime.h>

// STN fused, one block per image, 256 threads.
// Round-2 changes vs round-1:
//  - conv threads indexed row-major (i*8+o) -> conflict-free LDS row reads
//  - conv+maxpool fused (h-pool in regs, v-pool via shfl_xor) -> s_c1/s_c2 gone
//  - output staging overlaid on s_fc1w (dead after fc1)
//  - LDS ~39 KB -> 4 blocks/CU; __launch_bounds__(256,4) caps VGPR for 16 waves/CU

__launch_bounds__(256, 4)
__global__ void stn_fused_kernel(
    const float* __restrict__ x,
    const float* __restrict__ w1, const float* __restrict__ b1,
    const float* __restrict__ w2, const float* __restrict__ b2,
    const float* __restrict__ fc1w, const float* __restrict__ fc1b,
    const float* __restrict__ fc2w, const float* __restrict__ fc2b,
    float* __restrict__ out)
{
    __shared__ __align__(16) float s_img[3 * 28 * 28];    // 2352, CHW
    __shared__ __align__(16) float s_w1[8 * 3 * 7 * 7];   // 1176
    __shared__ __align__(16) float s_w2p[10 * 205];       // 2050, o-stride padded 200->205
    __shared__ __align__(16) float s_fc1w[32 * 90];       // 2880; reused as output staging
    __shared__ __align__(16) float s_fc2w[6 * 32];        // 192
    __shared__ __align__(16) float s_h1[8 * 11 * 12];     // pooled1, rows padded to 12
    __shared__ float s_h2[90];
    __shared__ float s_fch[32];
    __shared__ float s_theta[6];
    __shared__ float s_b1[8];
    __shared__ float s_b2[10];
    __shared__ float s_fc1b[32];
    __shared__ float s_fc2b[6];

    const int t = threadIdx.x;
    const int n = blockIdx.x;
    const float* img = x + (size_t)n * 2352;

    // ---- Stage A: cooperative loads (image HWC -> LDS CHW, weights)
    for (int i = t; i < 2352; i += 256) {
        int hw = i / 3;
        int c = i - 3 * hw;
        s_img[c * 784 + hw] = img[i];
    }
    for (int i = t; i < 1176; i += 256) s_w1[i] = w1[i];
    for (int i = t; i < 2000; i += 256) {
        int o = i / 200, r = i - 200 * o;
        s_w2p[o * 205 + r] = w2[i];
    }
    for (int i = t; i < 2880; i += 256) s_fc1w[i] = fc1w[i];
    if (t < 192) s_fc2w[t] = fc2w[t];
    if (t < 8)  s_b1[t] = b1[t];
    if (t < 10) s_b2[t] = b2[t];
    if (t < 32) s_fc1b[t] = fc1b[t];
    if (t < 6)  s_fc2b[t] = fc2b[t];
    __syncthreads();

    // ---- Stage B: conv1 (3->8, 7x7) + 2x2 maxpool + relu -> s_h1 [8][11][12]
    // t = i*8 + o: wave holds 8 distinct rows (distinct bank-groups) x 8 bcast channels.
    if (t < 176) {
        const int i = t >> 3, o = t & 7;
        float acc[22];
        const float bias = s_b1[o];
        #pragma unroll
        for (int j = 0; j < 22; ++j) acc[j] = bias;
        for (int c = 0; c < 3; ++c) {
            #pragma unroll
            for (int kh = 0; kh < 7; ++kh) {
                const float* irow = &s_img[c * 784 + (i + kh) * 28];
                float im[28];
                #pragma unroll
                for (int q = 0; q < 7; ++q) {
                    float4 v = ((const float4*)irow)[q];
                    im[4 * q + 0] = v.x; im[4 * q + 1] = v.y;
                    im[4 * q + 2] = v.z; im[4 * q + 3] = v.w;
                }
                const float* wr = &s_w1[(o * 3 + c) * 49 + kh * 7];
                float wv[7];
                #pragma unroll
                for (int q = 0; q < 7; ++q) wv[q] = wr[q];
                #pragma unroll
                for (int kw = 0; kw < 7; ++kw) {
                    #pragma unroll
                    for (int j = 0; j < 22; ++j)
                        acc[j] += im[j + kw] * wv[kw];
                }
            }
        }
        // horizontal pair-max in regs
        float hm[11];
        #pragma unroll
        for (int j = 0; j < 11; ++j) hm[j] = fmaxf(acc[2 * j], acc[2 * j + 1]);
        // vertical pair-max via shfl: partner row i^1 is lane^8 (same wave)
        #pragma unroll
        for (int j = 0; j < 11; ++j) {
            float v = __shfl_xor(hm[j], 8);
            hm[j] = fmaxf(hm[j], v);
        }
        if ((i & 1) == 0) {
            float* row = &s_h1[(o * 11 + (i >> 1)) * 12];
            #pragma unroll
            for (int j = 0; j < 11; ++j) row[j] = fmaxf(hm[j], 0.0f);
        }
    }
    __syncthreads();

    // ---- Stage D: conv2 (8->10, 5x5) + 2x2 maxpool + relu -> s_h2[90]
    // t = o*6 + i (o in 0..9, i in 0..5); only rows/cols 0..5 feed the 3x3 pool.
    if (t < 60) {
        const int o = t / 6, i = t - 6 * (t / 6);
        float acc2[6];
        const float bias = s_b2[o];
        #pragma unroll
        for (int j = 0; j < 6; ++j) acc2[j] = bias;
        for (int c = 0; c < 8; ++c) {
            #pragma unroll
            for (int kh = 0; kh < 5; ++kh) {
                const float* hrow = &s_h1[(c * 11 + i + kh) * 12];
                float im2[12];
                #pragma unroll
                for (int q = 0; q < 3; ++q) {
                    float4 v = ((const float4*)hrow)[q];
                    im2[4 * q + 0] = v.x; im2[4 * q + 1] = v.y;
                    im2[4 * q + 2] = v.z; im2[4 * q + 3] = v.w;
                }
                const float* wr = &s_w2p[o * 205 + (c * 5 + kh) * 5];
                float wv[5];
                #pragma unroll
                for (int q = 0; q < 5; ++q) wv[q] = wr[q];
                #pragma unroll
                for (int kw = 0; kw < 5; ++kw) {
                    #pragma unroll
                    for (int j = 0; j < 6; ++j)
                        acc2[j] += im2[j + kw] * wv[kw];
                }
            }
        }
        float hp[3];
        #pragma unroll
        for (int q = 0; q < 3; ++q) hp[q] = fmaxf(acc2[2 * q], acc2[2 * q + 1]);
        #pragma unroll
        for (int q = 0; q < 3; ++q) {
            float v = __shfl_xor(hp[q], 1);   // partner i^1 = lane^1
            hp[q] = fmaxf(hp[q], v);
        }
        if ((i & 1) == 0) {
            #pragma unroll
            for (int q = 0; q < 3; ++q)
                s_h2[o * 9 + (i >> 1) * 3 + q] = fmaxf(hp[q], 0.0f);
        }
    }
    __syncthreads();

    // ---- Stage F: fc1 (90->32) + relu
    if (t < 32) {
        float acc = s_fc1b[t];
        const float* wr = &s_fc1w[t * 90];
        #pragma unroll 6
        for (int j = 0; j < 90; ++j) acc += s_h2[j] * wr[j];
        s_fch[t] = fmaxf(acc, 0.0f);
    }
    __syncthreads();

    // ---- Stage G: fc2 (32->6) -> theta
    if (t < 6) {
        float acc = s_fc2b[t];
        const float* wr = &s_fc2w[t * 32];
        #pragma unroll
        for (int j = 0; j < 32; ++j) acc += s_fch[j] * wr[j];
        s_theta[t] = acc;
    }
    __syncthreads();

    const float t00 = s_theta[0], t01 = s_theta[1], t02 = s_theta[2];
    const float t10 = s_theta[3], t11 = s_theta[4], t12 = s_theta[5];

    // ---- Stage H: affine grid + bilinear sample -> staging overlaid on s_fc1w
    float* s_stage = s_fc1w;  // fc1w dead after Stage F; 2352 <= 2880
    for (int p = t; p < 784; p += 256) {
        int h = p / 28, w = p - 28 * h;
        float xs = (2.0f * w + 1.0f) * (1.0f / 28.0f) - 1.0f;
        float ys = (2.0f * h + 1.0f) * (1.0f / 28.0f) - 1.0f;
        float gx = t00 * xs + t01 * ys + t02;
        float gy = t10 * xs + t11 * ys + t12;
        float ix = ((gx + 1.0f) * 28.0f - 1.0f) * 0.5f;
        float iy = ((gy + 1.0f) * 28.0f - 1.0f) * 0.5f;
        float x0f = floorf(ix), y0f = floorf(iy);
        float wx1 = ix - x0f, wx0 = 1.0f - wx1;
        float wy1 = iy - y0f, wy0 = 1.0f - wy1;
        int x0 = (int)x0f, y0 = (int)y0f;
        int x1 = x0 + 1, y1 = y0 + 1;
        float fx0 = (x0 >= 0 && x0 < 28) ? 1.0f : 0.0f;
        float fx1 = (x1 >= 0 && x1 < 28) ? 1.0f : 0.0f;
        float fy0 = (y0 >= 0 && y0 < 28) ? 1.0f : 0.0f;
        float fy1 = (y1 >= 0 && y1 < 28) ? 1.0f : 0.0f;
        float w00 = wx0 * wy0 * fx0 * fy0;
        float w10 = wx1 * wy0 * fx1 * fy0;
        float w01 = wx0 * wy1 * fx0 * fy1;
        float w11 = wx1 * wy1 * fx1 * fy1;
        int cx0 = min(max(x0, 0), 27), cx1 = min(max(x1, 0), 27);
        int cy0 = min(max(y0, 0), 27), cy1 = min(max(y1, 0), 27);
        int i00 = cy0 * 28 + cx0, i10 = cy0 * 28 + cx1;
        int i01 = cy1 * 28 + cx0, i11 = cy1 * 28 + cx1;
        #pragma unroll
        for (int c = 0; c < 3; ++c) {
            const float* ic = &s_img[c * 784];
            float v = ic[i00] * w00 + ic[i10] * w10 + ic[i01] * w01 + ic[i11] * w11;
            s_stage[p * 3 + c] = v;  // HWC, matches output layout
        }
    }
    __syncthreads();

    // ---- Stage I: coalesced float4 copy staging -> global
    float* outp = out + (size_t)n * 2352;
    for (int i = t; i < 588; i += 256) {
        ((float4*)outp)[i] = ((const float4*)s_stage)[i];
    }
}

extern "C" void kernel_launch(void* const* d_in, const int* in_sizes, int n_in,
                              void* d_out, int out_size, void* d_ws, size_t ws_size,
                              hipStream_t stream) {
    const float* x     = (const float*)d_in[0];
    const float* w1    = (const float*)d_in[1];
    const float* b1    = (const float*)d_in[2];
    const float* w2    = (const float*)d_in[3];
    const float* b2    = (const float*)d_in[4];
    const float* fc1w  = (const float*)d_in[5];
    const float* fc1b  = (const float*)d_in[6];
    const float* fc2w  = (const float*)d_in[7];
    const float* fc2b  = (const float*)d_in[8];
    float* outp = (float*)d_out;

    const int n_img = 64 * 256;  // b*n
    stn_fused_kernel<<<dim3(n_img), dim3(256), 0, stream>>>(
        x, w1, b1, w2, b2, fc1w, fc1b, fc2w, fc2b, outp);
}